// Round 5
// baseline (492.621 us; speedup 1.0000x reference)
//
#include <hip/hip_runtime.h>
#include <hip/hip_cooperative_groups.h>

namespace cg = cooperative_groups;

#define N_NODES 50000
#define N_EDGES 300000
#define N_TOT   350000   // edges + self-loops
#define D       256
#define MPAD    50048    // N_NODES padded to multiple of 128 for GEMM
#define SCAN_B  196      // ceil(50000/256)
#define SETUP_GRID 512

typedef __attribute__((ext_vector_type(8))) short bf16x8;
typedef __attribute__((ext_vector_type(4))) float f32x4;
typedef __attribute__((ext_vector_type(8))) unsigned short u16x8;

__device__ __forceinline__ float bf2f(unsigned short b) {
    union { unsigned u; float f; } v; v.u = ((unsigned)b) << 16; return v.f;
}
__device__ __forceinline__ unsigned short f2bf(float f) {
    union { float f; unsigned u; } v; v.f = f;
    unsigned u = v.u;
    unsigned r = (u + 0x7FFFu + ((u >> 16) & 1u)) >> 16;   // round-nearest-even
    return (unsigned short)r;
}
__device__ __forceinline__ void g2lds16(const unsigned short* g, unsigned short* l) {
    __builtin_amdgcn_global_load_lds(
        (const __attribute__((address_space(1))) void*)g,
        (__attribute__((address_space(3))) void*)l, 16, 0, 0);
}

// ---- fused preprocessing (cooperative): zero+transpose+embed | hist | dis+scan |
//      block-scan | rowptr+fill ----
__global__ void __launch_bounds__(256) setup_kernel(
        const float* __restrict__ x, const int* __restrict__ ei,
        const float* __restrict__ We, const float* __restrict__ be,
        const float* __restrict__ W1, const float* __restrict__ W2,
        int* __restrict__ cnt, int* __restrict__ fc, float* __restrict__ dis,
        int* __restrict__ locs, int* __restrict__ bsum, int* __restrict__ rowptr,
        int* __restrict__ esrc, float* __restrict__ enorm,
        unsigned short* __restrict__ Wt1, unsigned short* __restrict__ Wt2,
        unsigned short* __restrict__ hA) {
    cg::grid_group grid = cg::this_grid();
    __shared__ int ws[4];
    int t = threadIdx.x;
    int tid = blockIdx.x * 256 + t;
    const int T = SETUP_GRID * 256;

    // ---- Phase A: zero counters, transpose weights, embed ----
    for (int i = tid; i < N_NODES; i += T) { cnt[i] = 0; fc[i] = 0; }
    for (int i = tid; i < 2 * D * D; i += T) {
        int wsel = i >> 16, rem = i & 65535;
        int tt = rem >> 8, b = rem & 255;              // read coalesced over b
        const float* W = wsel ? W2 : W1;
        unsigned short* Wt = wsel ? Wt2 : Wt1;
        Wt[b * D + tt] = f2bf(W[tt * D + b]);
    }
    {
        float w[11];
        #pragma unroll
        for (int k = 0; k < 11; ++k) w[k] = We[k * D + t];
        float bb = be[t];
        for (int g = blockIdx.x; g < MPAD / 8; g += SETUP_GRID) {
            #pragma unroll
            for (int ni = 0; ni < 8; ++ni) {
                int node = g * 8 + ni;
                float acc = 0.f;
                if (node < N_NODES) {
                    acc = bb;
                    #pragma unroll
                    for (int k = 0; k < 11; ++k) acc += x[node * 11 + k] * w[k];
                    acc = fmaxf(acc, 0.f);
                }
                hA[(size_t)node * D + t] = f2bf(acc);  // pad rows get 0
            }
        }
    }
    grid.sync();

    // ---- Phase B: degree histogram over dst ----
    for (int e = tid; e < N_TOT; e += T) {
        int dst = (e < N_EDGES) ? ei[N_EDGES + e] : (e - N_EDGES);
        atomicAdd(&cnt[dst], 1);
    }
    grid.sync();

    // ---- Phase C: deg_inv_sqrt + per-chunk (256) inclusive scans ----
    if (blockIdx.x < SCAN_B) {
        int i = blockIdx.x * 256 + t;
        int v = (i < N_NODES) ? cnt[i] : 0;
        if (i < N_NODES) dis[i] = rsqrtf((float)v);    // deg >= 1 (self-loop)
        int lane = t & 63, wv = t >> 6;
        int s = v;
        #pragma unroll
        for (int d = 1; d < 64; d <<= 1) {
            int u = __shfl_up(s, d, 64);
            if (lane >= d) s += u;
        }
        if (lane == 63) ws[wv] = s;
        __syncthreads();
        int off = 0;
        #pragma unroll
        for (int k = 0; k < 4; ++k) if (k < wv) off += ws[k];
        s += off;
        if (i < N_NODES) locs[i] = s;
        if (t == 255) bsum[blockIdx.x] = s;
    }
    grid.sync();

    // ---- Phase D: exclusive scan of the 196 chunk totals (block 0) ----
    if (blockIdx.x == 0) {
        int v = (t < SCAN_B) ? bsum[t] : 0;
        int lane = t & 63, wv = t >> 6;
        int s = v;
        #pragma unroll
        for (int d = 1; d < 64; d <<= 1) {
            int u = __shfl_up(s, d, 64);
            if (lane >= d) s += u;
        }
        if (lane == 63) ws[wv] = s;
        __syncthreads();
        int off = 0;
        #pragma unroll
        for (int k = 0; k < 4; ++k) if (k < wv) off += ws[k];
        s += off;
        if (t < SCAN_B) bsum[t] = s - v;               // exclusive offsets
    }
    grid.sync();

    // ---- Phase E: rowptr materialization + CSR fill (independent jobs) ----
    if (tid == 0) rowptr[0] = 0;
    for (int i = tid; i < N_NODES; i += T)
        rowptr[i + 1] = locs[i] + bsum[i >> 8];
    for (int e = tid; e < N_TOT; e += T) {
        int src, dst;
        if (e < N_EDGES) { src = ei[e]; dst = ei[N_EDGES + e]; }
        else             { src = dst = e - N_EDGES; }
        int base = bsum[dst >> 8] + ((dst & 255) ? locs[dst - 1] : 0);
        int pos = base + atomicAdd(&fc[dst], 1);
        esrc[pos]  = src;
        enorm[pos] = dis[src] * dis[dst];
    }
}

// ---- GEMM (m97-style): C[MPAD,256] = A @ W, W as Wt[n][k]; 128x128 tile, BK=32,
//      global_load_lds width-16 staging, ds_read_b128 frags, bf16 in/out, fp32 acc ----
__global__ __launch_bounds__(256) void gemm_kernel(const unsigned short* __restrict__ A,
                                                   const unsigned short* __restrict__ Bt,
                                                   unsigned short* __restrict__ C) {
    __shared__ unsigned short lA[128 * 32];
    __shared__ unsigned short lB[128 * 32];
    int t = threadIdx.x;
    int wv = t >> 6, lane = t & 63;
    int m0 = blockIdx.x * 128;
    int n0 = blockIdx.y * 128;
    int moff = (wv & 1) * 64, noff = (wv >> 1) * 64;
    int q = lane >> 4, r = lane & 15;

    int srow = t >> 2;            // 0..63: staged row within half-tile
    int skof = (t & 3) * 8;       // k-offset in elements (4 threads x 8 = 32)

    const unsigned short* Ag0 = A  + (size_t)(m0 + srow) * D + skof;
    const unsigned short* Ag1 = Ag0 + (size_t)64 * D;
    const unsigned short* Bg0 = Bt + (size_t)(n0 + srow) * D + skof;
    const unsigned short* Bg1 = Bg0 + (size_t)64 * D;
    unsigned short* lA0 = lA + t * 8;          // lane-contiguous: row-major [128][32]
    unsigned short* lA1 = lA0 + 64 * 32;
    unsigned short* lB0 = lB + t * 8;
    unsigned short* lB1 = lB0 + 64 * 32;

    f32x4 acc[4][4] = {};
    for (int kk = 0; kk < D; kk += 32) {
        __syncthreads();
        g2lds16(Ag0 + kk, lA0);
        g2lds16(Ag1 + kk, lA1);
        g2lds16(Bg0 + kk, lB0);
        g2lds16(Bg1 + kk, lB1);
        __syncthreads();
        bf16x8 a[4], b[4];
        #pragma unroll
        for (int mt = 0; mt < 4; ++mt)
            a[mt] = *(const bf16x8*)(lA + (moff + mt * 16 + r) * 32 + q * 8);
        #pragma unroll
        for (int nt = 0; nt < 4; ++nt)
            b[nt] = *(const bf16x8*)(lB + (noff + nt * 16 + r) * 32 + q * 8);
        #pragma unroll
        for (int mt = 0; mt < 4; ++mt)
            #pragma unroll
            for (int nt = 0; nt < 4; ++nt)
                acc[mt][nt] = __builtin_amdgcn_mfma_f32_16x16x32_bf16(a[mt], b[nt], acc[mt][nt], 0, 0, 0);
    }
    #pragma unroll
    for (int mt = 0; mt < 4; ++mt)
        #pragma unroll
        for (int nt = 0; nt < 4; ++nt) {
            int col  = n0 + noff + nt * 16 + r;
            int rowb = m0 + moff + mt * 16 + q * 4;
            #pragma unroll
            for (int i = 0; i < 4; ++i)
                C[(size_t)(rowb + i) * D + col] = f2bf(acc[mt][nt][i]);
        }
}

// ---- gather-aggregate: wave per node, 2 edges per trip, 16B/lane ----
__global__ __launch_bounds__(256) void agg_kernel(const unsigned short* __restrict__ hw,
                                                  const int* __restrict__ rowptr,
                                                  const int* __restrict__ esrc,
                                                  const float* __restrict__ enorm,
                                                  const float* __restrict__ bias,
                                                  unsigned short* __restrict__ out_bf,
                                                  float* __restrict__ out_f32,
                                                  int mode) {
    int wid  = threadIdx.x >> 6;
    int lane = threadIdx.x & 63;
    int node = blockIdx.x * 4 + wid;
    if (node >= N_NODES) return;
    int s0 = rowptr[node], s1 = rowptr[node + 1];
    int half = lane >> 5, hl = lane & 31;

    float acc[8] = {};
    for (int base = s0; base < s1; base += 64) {   // one trip in practice (deg << 64)
        int ec = s1 - base; if (ec > 64) ec = 64;
        int   srcl = 0; float nml = 0.f;
        if (lane < ec) { srcl = esrc[base + lane]; nml = enorm[base + lane]; }
        int it = (ec + 1) >> 1;
        for (int i = 0; i < it; ++i) {
            int   e  = 2 * i + half;
            int   s  = __shfl(srcl, e, 64);
            float nm = __shfl(nml, e, 64);
            u16x8 hv = *(const u16x8*)(hw + (size_t)s * D + hl * 8);
            #pragma unroll
            for (int k = 0; k < 8; ++k) acc[k] += nm * bf2f(hv[k]);
        }
    }
    #pragma unroll
    for (int k = 0; k < 8; ++k) acc[k] += __shfl_xor(acc[k], 32, 64);

    if (lane < 32) {
        int c = hl * 8;
        float4 bv0 = *(const float4*)(bias + c);
        float4 bv1 = *(const float4*)(bias + c + 4);
        acc[0] += bv0.x; acc[1] += bv0.y; acc[2] += bv0.z; acc[3] += bv0.w;
        acc[4] += bv1.x; acc[5] += bv1.y; acc[6] += bv1.z; acc[7] += bv1.w;
        if (mode) {
            u16x8 ov;
            #pragma unroll
            for (int k = 0; k < 8; ++k) ov[k] = f2bf(fmaxf(acc[k], 0.f));
            *(u16x8*)(out_bf + (size_t)node * D + c) = ov;
        } else {
            float4 o0 = { acc[0], acc[1], acc[2], acc[3] };
            float4 o1 = { acc[4], acc[5], acc[6], acc[7] };
            *(float4*)(out_f32 + (size_t)node * D + c)     = o0;
            *(float4*)(out_f32 + (size_t)node * D + c + 4) = o1;
        }
    }
}

extern "C" void kernel_launch(void* const* d_in, const int* in_sizes, int n_in,
                              void* d_out, int out_size, void* d_ws, size_t ws_size,
                              hipStream_t stream) {
    const float* x  = (const float*)d_in[0];
    const int*   ei = (const int*)d_in[1];
    const float* We = (const float*)d_in[2];
    const float* be = (const float*)d_in[3];
    const float* W1 = (const float*)d_in[4];
    const float* b1 = (const float*)d_in[5];
    const float* W2 = (const float*)d_in[6];
    const float* b2 = (const float*)d_in[7];
    float* out = (float*)d_out;

    char* w = (char*)d_ws;
    auto alloc = [&](size_t bytes) {
        char* p = w;
        w += (bytes + 255) & ~(size_t)255;
        return p;
    };
    int*            cnt    = (int*)alloc((size_t)N_NODES * 4);
    int*            fc     = (int*)alloc((size_t)N_NODES * 4);
    int*            rowptr = (int*)alloc((size_t)(N_NODES + 1) * 4);
    int*            locs   = (int*)alloc((size_t)N_NODES * 4);
    int*            bsum   = (int*)alloc((size_t)SCAN_B * 4);
    float*          dis    = (float*)alloc((size_t)N_NODES * 4);
    int*            esrc   = (int*)alloc((size_t)N_TOT * 4);
    float*          enorm  = (float*)alloc((size_t)N_TOT * 4);
    unsigned short* Wt1    = (unsigned short*)alloc((size_t)D * D * 2);
    unsigned short* Wt2    = (unsigned short*)alloc((size_t)D * D * 2);
    unsigned short* hA     = (unsigned short*)alloc((size_t)MPAD * D * 2);
    unsigned short* hW     = (unsigned short*)alloc((size_t)MPAD * D * 2);

    void* args[] = { (void*)&x, (void*)&ei, (void*)&We, (void*)&be,
                     (void*)&W1, (void*)&W2,
                     (void*)&cnt, (void*)&fc, (void*)&dis, (void*)&locs,
                     (void*)&bsum, (void*)&rowptr, (void*)&esrc, (void*)&enorm,
                     (void*)&Wt1, (void*)&Wt2, (void*)&hA };
    hipLaunchCooperativeKernel((const void*)setup_kernel, dim3(SETUP_GRID), dim3(256),
                               args, 0, stream);

    dim3 ggrid(MPAD / 128, 2);
    gemm_kernel<<<ggrid, 256, 0, stream>>>(hA, Wt1, hW);
    agg_kernel<<<(N_NODES + 3) / 4, 256, 0, stream>>>(hW, rowptr, esrc, enorm, b1, hA, nullptr, 1);

    gemm_kernel<<<ggrid, 256, 0, stream>>>(hA, Wt2, hW);
    agg_kernel<<<(N_NODES + 3) / 4, 256, 0, stream>>>(hW, rowptr, esrc, enorm, b2, nullptr, out, 0);
}

// Round 6
// 255.469 us; speedup vs baseline: 1.9283x; 1.9283x over previous
//
#include <hip/hip_runtime.h>

#define N_NODES 50000
#define N_EDGES 300000
#define N_TOT   350000   // edges + self-loops
#define D       256
#define MPAD    50048    // N_NODES padded to multiple of 128 for GEMM
#define SCAN_B  196      // ceil(50000/256)

typedef __attribute__((ext_vector_type(8))) short bf16x8;
typedef __attribute__((ext_vector_type(4))) float f32x4;
typedef __attribute__((ext_vector_type(8))) unsigned short u16x8;

__device__ __forceinline__ float bf2f(unsigned short b) {
    union { unsigned u; float f; } v; v.u = ((unsigned)b) << 16; return v.f;
}
__device__ __forceinline__ unsigned short f2bf(float f) {
    union { float f; unsigned u; } v; v.f = f;
    unsigned u = v.u;
    unsigned r = (u + 0x7FFFu + ((u >> 16) & 1u)) >> 16;   // round-nearest-even
    return (unsigned short)r;
}
__device__ __forceinline__ void g2lds16(const unsigned short* g, unsigned short* l) {
    __builtin_amdgcn_global_load_lds(
        (const __attribute__((address_space(1))) void*)g,
        (__attribute__((address_space(3))) void*)l, 16, 0, 0);
}

// ---- prep1: zero counters + transpose/cast W + embed (all independent) ----
// grid = 512 blocks x 256
__global__ __launch_bounds__(256) void prep1_kernel(
        const float* __restrict__ x, const float* __restrict__ We,
        const float* __restrict__ be, const float* __restrict__ W1,
        const float* __restrict__ W2,
        int* __restrict__ cnt, int* __restrict__ fc,
        unsigned short* __restrict__ Wt1, unsigned short* __restrict__ Wt2,
        unsigned short* __restrict__ hA) {
    int t = threadIdx.x;
    int tid = blockIdx.x * 256 + t;
    const int T = 512 * 256;
    for (int i = tid; i < N_NODES; i += T) { cnt[i] = 0; fc[i] = 0; }
    for (int i = tid; i < 2 * D * D; i += T) {
        int wsel = i >> 16, rem = i & 65535;
        int tt = rem >> 8, b = rem & 255;              // coalesced over b
        const float* W = wsel ? W2 : W1;
        unsigned short* Wt = wsel ? Wt2 : Wt1;
        Wt[b * D + tt] = f2bf(W[tt * D + b]);
    }
    float w[11];
    #pragma unroll
    for (int k = 0; k < 11; ++k) w[k] = We[k * D + t];
    float bb = be[t];
    for (int g = blockIdx.x; g < MPAD / 8; g += 512) {
        #pragma unroll
        for (int ni = 0; ni < 8; ++ni) {
            int node = g * 8 + ni;
            float acc = 0.f;
            if (node < N_NODES) {
                acc = bb;
                #pragma unroll
                for (int k = 0; k < 11; ++k) acc += x[node * 11 + k] * w[k];
                acc = fmaxf(acc, 0.f);
            }
            hA[(size_t)node * D + t] = f2bf(acc);      // pad rows get 0
        }
    }
}

// ---- degree histogram over dst (self-loops included) ----
__global__ void hist_kernel(const int* __restrict__ ei, int* __restrict__ cnt) {
    int e = blockIdx.x * 256 + threadIdx.x;
    if (e >= N_TOT) return;
    int dst = (e < N_EDGES) ? ei[N_EDGES + e] : (e - N_EDGES);
    atomicAdd(&cnt[dst], 1);
}

// ---- prep2: deg_inv_sqrt + per-256-chunk inclusive scan ----
__global__ void prep2_kernel(const int* __restrict__ cnt, float* __restrict__ dis,
                             int* __restrict__ locs, int* __restrict__ bsum) {
    __shared__ int ws[4];
    int t = threadIdx.x, lane = t & 63, wv = t >> 6;
    int i = blockIdx.x * 256 + t;
    int v = (i < N_NODES) ? cnt[i] : 0;
    if (i < N_NODES) dis[i] = rsqrtf((float)v);        // deg >= 1 (self-loop)
    int s = v;
    #pragma unroll
    for (int d = 1; d < 64; d <<= 1) {
        int u = __shfl_up(s, d, 64);
        if (lane >= d) s += u;
    }
    if (lane == 63) ws[wv] = s;
    __syncthreads();
    int off = 0;
    #pragma unroll
    for (int k = 0; k < 4; ++k) if (k < wv) off += ws[k];
    s += off;
    if (i < N_NODES) locs[i] = s;                      // inclusive local scan
    if (t == 255) bsum[blockIdx.x] = s;                // chunk total
}

// ---- scan2: exclusive scan of 196 chunk totals (1 block) ----
__global__ void scan2_kernel(int* __restrict__ bsum) {
    __shared__ int ws[4];
    int t = threadIdx.x, lane = t & 63, wv = t >> 6;
    int v = (t < SCAN_B) ? bsum[t] : 0;
    int s = v;
    #pragma unroll
    for (int d = 1; d < 64; d <<= 1) {
        int u = __shfl_up(s, d, 64);
        if (lane >= d) s += u;
    }
    if (lane == 63) ws[wv] = s;
    __syncthreads();
    int off = 0;
    #pragma unroll
    for (int k = 0; k < 4; ++k) if (k < wv) off += ws[k];
    s += off;
    if (t < SCAN_B) bsum[t] = s - v;                   // exclusive block offsets
}

// ---- prep3: rowptr materialization + CSR fill (both depend only on locs/bsum) ----
__global__ void prep3_kernel(const int* __restrict__ ei, const int* __restrict__ locs,
                             const int* __restrict__ bsum, const float* __restrict__ dis,
                             int* __restrict__ fc, int* __restrict__ rowptr,
                             int* __restrict__ esrc, float* __restrict__ enorm) {
    int tid = blockIdx.x * 256 + threadIdx.x;
    if (tid == 0) rowptr[0] = 0;
    if (tid < N_NODES)
        rowptr[tid + 1] = locs[tid] + bsum[tid >> 8];
    if (tid < N_TOT) {
        int src, dst;
        if (tid < N_EDGES) { src = ei[tid]; dst = ei[N_EDGES + tid]; }
        else               { src = dst = tid - N_EDGES; }
        int base = bsum[dst >> 8] + ((dst & 255) ? locs[dst - 1] : 0);
        int pos = base + atomicAdd(&fc[dst], 1);
        esrc[pos]  = src;
        enorm[pos] = dis[src] * dis[dst];
    }
}

// ---- GEMM (m97-style): C[MPAD,256] = A @ W, W as Wt[n][k]; 128x128 tile, BK=32,
//      global_load_lds width-16 staging, ds_read_b128 frags, bf16 in/out, fp32 acc ----
__global__ __launch_bounds__(256) void gemm_kernel(const unsigned short* __restrict__ A,
                                                   const unsigned short* __restrict__ Bt,
                                                   unsigned short* __restrict__ C) {
    __shared__ unsigned short lA[128 * 32];
    __shared__ unsigned short lB[128 * 32];
    int t = threadIdx.x;
    int wv = t >> 6, lane = t & 63;
    int m0 = blockIdx.x * 128;
    int n0 = blockIdx.y * 128;
    int moff = (wv & 1) * 64, noff = (wv >> 1) * 64;
    int q = lane >> 4, r = lane & 15;

    int srow = t >> 2;            // 0..63: staged row within half-tile
    int skof = (t & 3) * 8;       // k-offset in elements

    const unsigned short* Ag0 = A  + (size_t)(m0 + srow) * D + skof;
    const unsigned short* Ag1 = Ag0 + (size_t)64 * D;
    const unsigned short* Bg0 = Bt + (size_t)(n0 + srow) * D + skof;
    const unsigned short* Bg1 = Bg0 + (size_t)64 * D;
    unsigned short* lA0 = lA + t * 8;          // row-major [128][32], lane-contiguous
    unsigned short* lA1 = lA0 + 64 * 32;
    unsigned short* lB0 = lB + t * 8;
    unsigned short* lB1 = lB0 + 64 * 32;

    f32x4 acc[4][4] = {};
    for (int kk = 0; kk < D; kk += 32) {
        __syncthreads();
        g2lds16(Ag0 + kk, lA0);
        g2lds16(Ag1 + kk, lA1);
        g2lds16(Bg0 + kk, lB0);
        g2lds16(Bg1 + kk, lB1);
        __syncthreads();
        bf16x8 a[4], b[4];
        #pragma unroll
        for (int mt = 0; mt < 4; ++mt)
            a[mt] = *(const bf16x8*)(lA + (moff + mt * 16 + r) * 32 + q * 8);
        #pragma unroll
        for (int nt = 0; nt < 4; ++nt)
            b[nt] = *(const bf16x8*)(lB + (noff + nt * 16 + r) * 32 + q * 8);
        #pragma unroll
        for (int mt = 0; mt < 4; ++mt)
            #pragma unroll
            for (int nt = 0; nt < 4; ++nt)
                acc[mt][nt] = __builtin_amdgcn_mfma_f32_16x16x32_bf16(a[mt], b[nt], acc[mt][nt], 0, 0, 0);
    }
    #pragma unroll
    for (int mt = 0; mt < 4; ++mt)
        #pragma unroll
        for (int nt = 0; nt < 4; ++nt) {
            int col  = n0 + noff + nt * 16 + r;
            int rowb = m0 + moff + mt * 16 + q * 4;
            #pragma unroll
            for (int i = 0; i < 4; ++i)
                C[(size_t)(rowb + i) * D + col] = f2bf(acc[mt][nt][i]);
        }
}

// ---- gather-aggregate: wave per node, 2 edges per trip, 16B/lane ----
__global__ __launch_bounds__(256) void agg_kernel(const unsigned short* __restrict__ hw,
                                                  const int* __restrict__ rowptr,
                                                  const int* __restrict__ esrc,
                                                  const float* __restrict__ enorm,
                                                  const float* __restrict__ bias,
                                                  unsigned short* __restrict__ out_bf,
                                                  float* __restrict__ out_f32,
                                                  int mode) {
    int wid  = threadIdx.x >> 6;
    int lane = threadIdx.x & 63;
    int node = blockIdx.x * 4 + wid;
    if (node >= N_NODES) return;
    int s0 = rowptr[node], s1 = rowptr[node + 1];
    int half = lane >> 5, hl = lane & 31;

    float acc[8] = {};
    for (int base = s0; base < s1; base += 64) {   // one trip in practice
        int ec = s1 - base; if (ec > 64) ec = 64;
        int   srcl = 0; float nml = 0.f;
        if (lane < ec) { srcl = esrc[base + lane]; nml = enorm[base + lane]; }
        int it = (ec + 1) >> 1;
        for (int i = 0; i < it; ++i) {
            int   e  = 2 * i + half;
            int   s  = __shfl(srcl, e, 64);
            float nm = __shfl(nml, e, 64);
            u16x8 hv = *(const u16x8*)(hw + (size_t)s * D + hl * 8);
            #pragma unroll
            for (int k = 0; k < 8; ++k) acc[k] += nm * bf2f(hv[k]);
        }
    }
    #pragma unroll
    for (int k = 0; k < 8; ++k) acc[k] += __shfl_xor(acc[k], 32, 64);

    if (lane < 32) {
        int c = hl * 8;
        float4 bv0 = *(const float4*)(bias + c);
        float4 bv1 = *(const float4*)(bias + c + 4);
        acc[0] += bv0.x; acc[1] += bv0.y; acc[2] += bv0.z; acc[3] += bv0.w;
        acc[4] += bv1.x; acc[5] += bv1.y; acc[6] += bv1.z; acc[7] += bv1.w;
        if (mode) {
            u16x8 ov;
            #pragma unroll
            for (int k = 0; k < 8; ++k) ov[k] = f2bf(fmaxf(acc[k], 0.f));
            *(u16x8*)(out_bf + (size_t)node * D + c) = ov;
        } else {
            float4 o0 = { acc[0], acc[1], acc[2], acc[3] };
            float4 o1 = { acc[4], acc[5], acc[6], acc[7] };
            *(float4*)(out_f32 + (size_t)node * D + c)     = o0;
            *(float4*)(out_f32 + (size_t)node * D + c + 4) = o1;
        }
    }
}

extern "C" void kernel_launch(void* const* d_in, const int* in_sizes, int n_in,
                              void* d_out, int out_size, void* d_ws, size_t ws_size,
                              hipStream_t stream) {
    const float* x  = (const float*)d_in[0];
    const int*   ei = (const int*)d_in[1];
    const float* We = (const float*)d_in[2];
    const float* be = (const float*)d_in[3];
    const float* W1 = (const float*)d_in[4];
    const float* b1 = (const float*)d_in[5];
    const float* W2 = (const float*)d_in[6];
    const float* b2 = (const float*)d_in[7];
    float* out = (float*)d_out;

    char* w = (char*)d_ws;
    auto alloc = [&](size_t bytes) {
        char* p = w;
        w += (bytes + 255) & ~(size_t)255;
        return p;
    };
    int*            cnt    = (int*)alloc((size_t)N_NODES * 4);
    int*            fc     = (int*)alloc((size_t)N_NODES * 4);
    int*            rowptr = (int*)alloc((size_t)(N_NODES + 1) * 4);
    int*            locs   = (int*)alloc((size_t)N_NODES * 4);
    int*            bsum   = (int*)alloc((size_t)SCAN_B * 4);
    float*          dis    = (float*)alloc((size_t)N_NODES * 4);
    int*            esrc   = (int*)alloc((size_t)N_TOT * 4);
    float*          enorm  = (float*)alloc((size_t)N_TOT * 4);
    unsigned short* Wt1    = (unsigned short*)alloc((size_t)D * D * 2);
    unsigned short* Wt2    = (unsigned short*)alloc((size_t)D * D * 2);
    unsigned short* hA     = (unsigned short*)alloc((size_t)MPAD * D * 2);
    unsigned short* hW     = (unsigned short*)alloc((size_t)MPAD * D * 2);

    prep1_kernel<<<512, 256, 0, stream>>>(x, We, be, W1, W2, cnt, fc, Wt1, Wt2, hA);
    hist_kernel<<<(N_TOT + 255) / 256, 256, 0, stream>>>(ei, cnt);
    prep2_kernel<<<SCAN_B, 256, 0, stream>>>(cnt, dis, locs, bsum);
    scan2_kernel<<<1, 256, 0, stream>>>(bsum);
    prep3_kernel<<<(N_TOT + 255) / 256, 256, 0, stream>>>(ei, locs, bsum, dis, fc,
                                                          rowptr, esrc, enorm);

    dim3 ggrid(MPAD / 128, 2);
    gemm_kernel<<<ggrid, 256, 0, stream>>>(hA, Wt1, hW);
    agg_kernel<<<(N_NODES + 3) / 4, 256, 0, stream>>>(hW, rowptr, esrc, enorm, b1, hA, nullptr, 1);

    gemm_kernel<<<ggrid, 256, 0, stream>>>(hA, Wt2, hW);
    agg_kernel<<<(N_NODES + 3) / 4, 256, 0, stream>>>(hW, rowptr, esrc, enorm, b2, nullptr, out, 0);
}